// Round 20
// baseline (286.621 us; speedup 1.0000x reference)
//
#include <hip/hip_runtime.h>
#include <hip/hip_bf16.h>

typedef __bf16 bf16;
typedef __bf16 bf16x8 __attribute__((ext_vector_type(8)));
typedef __bf16 bf16x4 __attribute__((ext_vector_type(4)));
typedef float  f32x4  __attribute__((ext_vector_type(4)));

#define MFMA(a,b,c) __builtin_amdgcn_mfma_f32_16x16x32_bf16(a,b,c,0,0,0)
#define EXP2F(x) __builtin_amdgcn_exp2f(x)

__device__ __forceinline__ void gload16(const void* g, void* l) {
  __builtin_amdgcn_global_load_lds((__attribute__((address_space(1))) void*)(g),
                                   (__attribute__((address_space(3))) void*)(l), 16, 0, 0);
}

// ---------------- fused fp32 -> bf16 cast (7 segments, one launch) ----------
struct CastSegs {
  const float* src[7];
  bf16* dst[7];
  int cum[8];
};

__global__ void cast_multi(CastSegs s) {
  int i = blockIdx.x * 256 + threadIdx.x;
  if (i >= s.cum[7]) return;
  int k = 0;
  #pragma unroll
  for (int j = 1; j < 7; ++j) if (i >= s.cum[j]) k = j;
  int off = i - s.cum[k];
  const float4* p = (const float4*)s.src[k];
  float4 a = p[2*off], b = p[2*off+1];
  bf16x8 v;
  v[0]=(bf16)a.x; v[1]=(bf16)a.y; v[2]=(bf16)a.z; v[3]=(bf16)a.w;
  v[4]=(bf16)b.x; v[5]=(bf16)b.y; v[6]=(bf16)b.z; v[7]=(bf16)b.w;
  *(bf16x8*)(s.dst[k] + (size_t)8*off) = v;
}

__device__ __forceinline__ float gelu_t(float s) {
  float u = s * (0.7978845608f + 0.0356774081f * s * s);
  return s / (1.0f + EXP2F(-2.885390082f * u));
}

#define LGKM0_FENCE() { asm volatile("s_waitcnt lgkmcnt(0)" ::: "memory"); \
                        __builtin_amdgcn_sched_barrier(0); }

// Shared epilogue semantics (both GEMM kernels):
// EPI 0: QKV — K/Q blocks -> outb bf16; V blocks (n0>=2048) -> vt[bh][dd][p]
// EPI 1: + addb (bf16) -> outb bf16           [W_O: x1 = z@Wo + x]
// EPI 2: + bias, GELU -> outb bf16            [MLP1]
// EPI 3: + bias + addb (bf16) -> outf f32     [MLP2 final]

// ============ 256x256 GEMM, 3 barriers/K-tile, C = A @ B^T ==================
// ph1: read A_lo frags + ALL B frags; stage A_hi(t+1)->buf^1 (readers: t-1).
// ph2: MM(0,*) (32 MFMAs); reload A_hi frags; stage B(t+2)->cur (B-reads ended ph1).
// ph3: MM(1,*) (32 MFMAs); stage A_lo(t+2)->cur (A-reads ended ph2); vmcnt; bar.
#define LDA_PH(MI2) { _Pragma("unroll") for (int i = 0; i < 4; i++) { \
    af[i][0] = *(const bf16x8*)(lds + ab + ((((MI2)<<2)+i) << 11) + rdswz); \
    af[i][1] = *(const bf16x8*)(lds + ab + ((((MI2)<<2)+i) << 11) + 1024 + rdswz); } }

#define LDB_PH(NI2) { _Pragma("unroll") for (int n = 0; n < 2; n++) { \
    bfr[((NI2)<<1)+n][0] = *(const bf16x8*)(lds + bb + (((((NI2)<<1)+n)) << 11) + rdswz); \
    bfr[((NI2)<<1)+n][1] = *(const bf16x8*)(lds + bb + (((((NI2)<<1)+n)) << 11) + 1024 + rdswz); } }

#define MM_PH(MI2, NI2) { __builtin_amdgcn_s_setprio(1); \
    _Pragma("unroll") for (int i = 0; i < 4; i++) \
      _Pragma("unroll") for (int n = 0; n < 2; n++) { \
        acc[((MI2)<<2)+i][((NI2)<<1)+n] = MFMA(af[i][0], bfr[((NI2)<<1)+n][0], acc[((MI2)<<2)+i][((NI2)<<1)+n]); \
        acc[((MI2)<<2)+i][((NI2)<<1)+n] = MFMA(af[i][1], bfr[((NI2)<<1)+n][1], acc[((MI2)<<2)+i][((NI2)<<1)+n]); } \
    __builtin_amdgcn_s_setprio(0); }

#define GTILE(CUR, S1, S2, VM) { \
    const int ab = ((CUR) << 16) + (wm << 14); \
    const int bb = ((CUR) << 16) + 32768 + (wn << 13); \
    LDA_PH(0); LDB_PH(0); LDB_PH(1); \
    if (S1) STG(sA, (CUR)^1, 0, 1, t + 1); \
    asm volatile("s_waitcnt lgkmcnt(8)" ::: "memory"); \
    __builtin_amdgcn_s_barrier(); LGKM0_FENCE(); \
    MM_PH(0, 0); MM_PH(0, 1); \
    LDA_PH(1); \
    if (S2) { STG(sB, (CUR), 1, 0, t + 2); STG(sB, (CUR), 1, 1, t + 2); } \
    __builtin_amdgcn_s_barrier(); LGKM0_FENCE(); \
    MM_PH(1, 0); \
    if (S2) STG(sA, (CUR), 0, 0, t + 2); \
    MM_PH(1, 1); \
    asm volatile("s_waitcnt vmcnt(" #VM ")" ::: "memory"); \
    __builtin_amdgcn_s_barrier(); \
    __builtin_amdgcn_sched_barrier(0); }

template<int EPI>
__global__ __launch_bounds__(512, 2) void gemm256(
    const bf16* __restrict__ A, const bf16* __restrict__ B,
    float* __restrict__ outf, bf16* __restrict__ outb,
    const bf16* __restrict__ addb, const float* __restrict__ bias,
    bf16* __restrict__ vtb,
    int M, int N, int K, int gx)
{
  __shared__ __attribute__((aligned(128))) char lds[131072];
  const int tid = threadIdx.x;
  const int w = tid >> 6, l = tid & 63, lg = l >> 4, li = l & 15;
  const int wm = w >> 2, wn = w & 3;

  const int nwg = gridDim.x, orig = blockIdx.x;
  const int q = nwg >> 3, r = nwg & 7;
  const int xcd = orig & 7, pos = orig >> 3;
  const int wg = (xcd < r ? xcd*(q+1) : r*(q+1) + (xcd-r)*q) + pos;
  const int m0 = (wg / gx) << 8, n0 = (wg % gx) << 8;

  const int NT = K >> 6;

  const int srow = ((tid >> 7) << 4) + ((tid >> 2) & 15);
  const int scol = (((tid >> 6) & 1) << 5) + (((tid & 3) << 3) ^ (((tid >> 5) & 1) << 4));
  const bf16* sA = A + (size_t)(m0 + srow) * K + scol;
  const bf16* sB = B + (size_t)(n0 + srow) * K + scol;
  char* const myl = lds + (w << 10);

  auto STG = [&](const bf16* s0, int buf, int isB, int h, int tt) {
    const bf16* g = s0 + ((size_t)(h << 7)) * K + ((size_t)tt << 6);
    char* lb = myl + (buf << 16) + (isB << 15) + (h << 14);
    gload16(g, lb);
    gload16(g + ((size_t)K << 6), lb + 8192);
  };

  const int rdswz = (li << 6) + ((lg << 4) ^ ((li & 8) << 2));

  f32x4 acc[8][4] = {};
  bf16x8 af[4][2], bfr[4][2];

  STG(sB, 0, 1, 0, 0); STG(sB, 0, 1, 1, 0); STG(sA, 0, 0, 0, 0); STG(sA, 0, 0, 1, 0);
  asm volatile("s_waitcnt vmcnt(4)" ::: "memory");
  STG(sB, 1, 1, 0, 1); STG(sB, 1, 1, 1, 1); STG(sA, 1, 0, 0, 1);
  asm volatile("s_waitcnt vmcnt(6)" ::: "memory");
  __builtin_amdgcn_s_barrier();
  __builtin_amdgcn_sched_barrier(0);

  int t = 0;
  for (int tt = 0; tt + 3 < NT; tt += 2) {
    t = tt;     GTILE(0, 1, 1, 6);
    t = tt + 1; GTILE(1, 1, 1, 6);
  }
  t = NT - 2; GTILE(0, 1, 0, 0);
  t = NT - 1; GTILE(1, 0, 0, 0);

  if (EPI == 0 && n0 >= 2048) {
    #pragma unroll
    for (int mi = 0; mi < 8; mi++) {
      const int row = m0 + (wm << 7) + (mi << 4) + (lg << 2);
      const int p = row & 2047;
      const size_t bhb = (size_t)((row >> 11) << 4);
      #pragma unroll
      for (int ni = 0; ni < 4; ni++) {
        const int col = n0 + (wn << 6) + (ni << 4) + li;
        const int hh = (col >> 6) & 15, dd = col & 63;
        bf16x4 pk;
        pk[0] = (bf16)acc[mi][ni][0]; pk[1] = (bf16)acc[mi][ni][1];
        pk[2] = (bf16)acc[mi][ni][2]; pk[3] = (bf16)acc[mi][ni][3];
        *(bf16x4*)(vtb + ((bhb + hh) * 64 + dd) * 2048 + p) = pk;
      }
    }
    return;
  }

  #pragma unroll
  for (int mi = 0; mi < 8; mi++) {
    const int row = m0 + (wm << 7) + (mi << 4) + (lg << 2);
    #pragma unroll
    for (int ni = 0; ni < 4; ni++) {
      const int col = n0 + (wn << 6) + (ni << 4) + li;
      #pragma unroll
      for (int r2 = 0; r2 < 4; r2++) {
        const size_t idx = (size_t)(row + r2) * N + col;
        float v = acc[mi][ni][r2];
        if (EPI == 0) {
          outb[idx] = (bf16)v;
        } else if (EPI == 1) {
          outb[idx] = (bf16)(v + (float)addb[idx]);
        } else if (EPI == 2) {
          outb[idx] = (bf16)gelu_t(v + bias[col]);
        } else {
          outf[idx] = v + bias[col] + (float)addb[idx];
        }
      }
    }
  }
}

// ============ 256x128 GEMM, 3 barriers/K-tile, C = A @ B^T ==================
#define N_LDA2(BMI) { _Pragma("unroll") for (int i = 0; i < 2; i++) { \
    af[i][0] = *(const bf16x8*)(lds + abase + (((BMI)+i) << 11) + rdswz); \
    af[i][1] = *(const bf16x8*)(lds + abase + (((BMI)+i) << 11) + 1024 + rdswz); } }

#define N_LDB2(BNI) { _Pragma("unroll") for (int n = 0; n < 2; n++) { \
    bfr[(BNI)+n][0] = *(const bf16x8*)(lds + bbase + (((BNI)+n) << 11) + rdswz); \
    bfr[(BNI)+n][1] = *(const bf16x8*)(lds + bbase + (((BNI)+n) << 11) + 1024 + rdswz); } }

#define N_MMQ(MB, NB) { __builtin_amdgcn_s_setprio(1); \
    _Pragma("unroll") for (int i = 0; i < 2; i++) \
      _Pragma("unroll") for (int n = 0; n < 2; n++) { \
        acc[((MB)<<1)+i][((NB)<<1)+n] = MFMA(af[i][0], bfr[((NB)<<1)+n][0], acc[((MB)<<1)+i][((NB)<<1)+n]); \
        acc[((MB)<<1)+i][((NB)<<1)+n] = MFMA(af[i][1], bfr[((NB)<<1)+n][1], acc[((MB)<<1)+i][((NB)<<1)+n]); } \
    __builtin_amdgcn_s_setprio(0); }

#define NTILE(CUR, S1, S2, VM) { \
    const int abase = (CUR) * 49152 + ((wm >> 1) << 14) + ((wm & 1) << 13); \
    const int bbase = (CUR) * 49152 + 32768 + (wn << 13); \
    N_LDA2(0); N_LDB2(0); N_LDB2(2); \
    if (S1) STA((CUR)^1, 1, t + 1); \
    __builtin_amdgcn_s_barrier(); LGKM0_FENCE(); \
    N_MMQ(0, 0); N_MMQ(0, 1); \
    N_LDA2(2); \
    if (S2) { STB((CUR), 0, t + 2); STB((CUR), 1, t + 2); } \
    __builtin_amdgcn_s_barrier(); LGKM0_FENCE(); \
    N_MMQ(1, 0); \
    if (S2) STA((CUR), 0, t + 2); \
    N_MMQ(1, 1); \
    asm volatile("s_waitcnt vmcnt(" #VM ")" ::: "memory"); \
    __builtin_amdgcn_s_barrier(); \
    __builtin_amdgcn_sched_barrier(0); }

template<int EPI>
__global__ __launch_bounds__(512, 2) void gemm128n(
    const bf16* __restrict__ A, const bf16* __restrict__ B,
    float* __restrict__ outf, bf16* __restrict__ outb,
    const bf16* __restrict__ addb, const float* __restrict__ bias,
    bf16* __restrict__ vtb,
    int M, int N, int K, int gx)
{
  __shared__ __attribute__((aligned(128))) char lds[98304];
  const int tid = threadIdx.x;
  const int w = tid >> 6, l = tid & 63, lg = l >> 4, li = l & 15;
  const int wm = w >> 1, wn = w & 1;

  const int nwg = gridDim.x, orig = blockIdx.x;
  const int q = nwg >> 3, r = nwg & 7;
  const int xcd = orig & 7, pos = orig >> 3;
  const int wg = (xcd < r ? xcd*(q+1) : r*(q+1) + (xcd-r)*q) + pos;
  const int m0 = (wg / gx) << 8, n0 = (wg % gx) << 7;

  const int NT = K >> 6;

  const int srow = ((tid >> 7) << 4) + ((tid >> 2) & 15);
  const int scol = (((tid >> 6) & 1) << 5) + (((tid & 3) << 3) ^ (((tid >> 5) & 1) << 4));
  const bf16* sA = A + (size_t)(m0 + srow) * K + scol;
  const bf16* sB = B + (size_t)(n0 + srow) * K + scol;
  char* const myl = lds + (w << 10);

  auto STA = [&](int buf, int h, int tt) {
    const bf16* g = sA + ((size_t)(h << 7)) * K + ((size_t)tt << 6);
    char* lb = myl + buf * 49152 + (h << 14);
    gload16(g, lb);
    gload16(g + ((size_t)K << 6), lb + 8192);
  };
  auto STB = [&](int buf, int h, int tt) {
    const bf16* g = sB + ((size_t)(h << 6)) * K + ((size_t)tt << 6);
    gload16(g, myl + buf * 49152 + 32768 + (h << 13));
  };

  const int rdswz = (li << 6) + ((lg << 4) ^ ((li & 8) << 2));

  f32x4 acc[4][4] = {};
  bf16x8 af[2][2], bfr[4][2];

  STB(0, 0, 0); STB(0, 1, 0); STA(0, 0, 0); STA(0, 1, 0);
  STB(1, 0, 1); STB(1, 1, 1); STA(1, 0, 1);
  asm volatile("s_waitcnt vmcnt(4)" ::: "memory");
  __builtin_amdgcn_s_barrier();
  __builtin_amdgcn_sched_barrier(0);

  int t = 0;
  for (int tt = 0; tt + 3 < NT; tt += 2) {
    t = tt;     NTILE(0, 1, 1, 4);
    t = tt + 1; NTILE(1, 1, 1, 4);
  }
  t = NT - 2; NTILE(0, 1, 0, 0);
  t = NT - 1; NTILE(1, 0, 0, 0);

  if (EPI == 0 && n0 >= 2048) {
    #pragma unroll
    for (int mi = 0; mi < 4; mi++) {
      const int row = m0 + (wm << 6) + (mi << 4) + (lg << 2);
      const int p = row & 2047;
      const size_t bhb = (size_t)((row >> 11) << 4);
      #pragma unroll
      for (int ni = 0; ni < 4; ni++) {
        const int col = n0 + (wn << 6) + (ni << 4) + li;
        const int hh = (col >> 6) & 15, dd = col & 63;
        bf16x4 pk;
        pk[0] = (bf16)acc[mi][ni][0]; pk[1] = (bf16)acc[mi][ni][1];
        pk[2] = (bf16)acc[mi][ni][2]; pk[3] = (bf16)acc[mi][ni][3];
        *(bf16x4*)(vtb + ((bhb + hh) * 64 + dd) * 2048 + p) = pk;
      }
    }
    return;
  }

  #pragma unroll
  for (int mi = 0; mi < 4; mi++) {
    const int row = m0 + (wm << 6) + (mi << 4) + (lg << 2);
    #pragma unroll
    for (int ni = 0; ni < 4; ni++) {
      const int col = n0 + (wn << 6) + (ni << 4) + li;
      #pragma unroll
      for (int r2 = 0; r2 < 4; r2++) {
        const size_t idx = (size_t)(row + r2) * N + col;
        float v = acc[mi][ni][r2];
        if (EPI == 0) {
          outb[idx] = (bf16)v;
        } else if (EPI == 1) {
          outb[idx] = (bf16)(v + (float)addb[idx]);
        } else if (EPI == 2) {
          outb[idx] = (bf16)gelu_t(v + bias[col]);
        } else {
          outf[idx] = v + bias[col] + (float)addb[idx];
        }
      }
    }
  }
}

// ---------------- causal flash attention (v8: KVBLK=128, 8-wave blocks) ------
__global__ __launch_bounds__(512, 2) void attn_kernel(const bf16* __restrict__ qkv,
                                                      const bf16* __restrict__ vt,
                                                      bf16* __restrict__ z)
{
  __shared__ bf16 Ksh[2][2*64*64];
  __shared__ bf16 Vsh[2][2*64*64];
  __shared__ bf16 Pl[8*16*64];

  const int tid = threadIdx.x;
  const int w = tid >> 6, l = tid & 63, lg = l >> 4, li = l & 15;
  const int orig = blockIdx.x;
  const int xcd = orig & 7, sub = orig >> 3;
  const int bh = (xcd << 3) + (sub >> 3);
  const int pr = sub & 7;
  const int h = bh & 15, b = bh >> 4;
  const size_t tb = (size_t)b * 2048;

  const int srow = tid >> 3, sc = tid & 7;
  const bf16* Kg = qkv + (tb + srow) * 3072 + 1024 + (h << 6) + ((sc ^ (srow & 7)) << 3);
  const bf16* Vg = vt + ((size_t)bh * 64 + srow) * 2048 + ((sc ^ (srow & 7)) << 3);

  char* pw = (char*)Pl + (w << 11) + li * 128;
  const int psw = (li & 3) << 5;

  for (int hf = 0; hf < 2; ++hf) {
    const int qt = hf ? pr : (15 - pr);
    const int qw = (qt << 7) + (w << 4);

    const bf16* Qp = qkv + (tb + qw + li) * 3072 + (h << 6);
    bf16x8 qa0 = *(const bf16x8*)(Qp + (lg << 3));
    bf16x8 qa1 = *(const bf16x8*)(Qp + 32 + (lg << 3));
    #pragma unroll
    for (int e = 0; e < 8; e++) {
      qa0[e] = (bf16)((float)qa0[e] * 0.1803368801f);
      qa1[e] = (bf16)((float)qa1[e] * 0.1803368801f);
    }

    f32x4 zacc[4] = {};
    float lS = 0.f;
    const int nkt = qt + 1;

    gload16(Kg,                    (bf16*)Ksh[0] + (w << 9));
    gload16(Kg + (size_t)64*3072,  (bf16*)Ksh[0] + 4096 + (w << 9));
    gload16(Vg,                    (bf16*)Vsh[0] + (w << 9));
    gload16(Vg + 64,               (bf16*)Vsh[0] + 4096 + (w << 9));
    __syncthreads();

    for (int kt = 0; kt < nkt; ++kt) {
      const int cur = kt & 1;
      const int kb = kt << 7;

      if (kt + 1 < nkt) {
        const int nb = cur ^ 1;
        gload16(Kg + (size_t)(kb + 128) * 3072, (bf16*)Ksh[nb] + (w << 9));
        gload16(Kg + (size_t)(kb + 192) * 3072, (bf16*)Ksh[nb] + 4096 + (w << 9));
        gload16(Vg + kb + 128,                  (bf16*)Vsh[nb] + (w << 9));
        gload16(Vg + kb + 192,                  (bf16*)Vsh[nb] + 4096 + (w << 9));
      }

      #pragma unroll
      for (int half = 0; half < 2; ++half) {
        const int pb = kb + (half << 6);
        const char* kbase = (const char*)Ksh[cur] + (half << 13);
        const char* vbase = (const char*)Vsh[cur] + (half << 13);

        f32x4 s[4];
        __builtin_amdgcn_s_setprio(1);
        #pragma unroll
        for (int sub2 = 0; sub2 < 4; ++sub2) {
          const char* kr = kbase + ((sub2 << 4) + li) * 128;
          const int c0 = (lg ^ (li & 7)) << 4;
          bf16x8 kb0 = *(const bf16x8*)(kr + c0);
          bf16x8 kb1 = *(const bf16x8*)(kr + (c0 ^ 64));
          f32x4 a2 = {};
          a2 = MFMA(kb0, qa0, a2);
          a2 = MFMA(kb1, qa1, a2);
          s[sub2] = a2;
        }
        __builtin_amdgcn_s_setprio(0);

        if (pb + 63 > qw) {
          #pragma unroll
          for (int sub2 = 0; sub2 < 4; ++sub2)
            #pragma unroll
            for (int r = 0; r < 4; ++r)
              if (pb + (sub2 << 4) + (lg << 2) + r > qw + li) s[sub2][r] = -1e30f;
        }

        f32x4 p[4];
        #pragma unroll
        for (int sub2 = 0; sub2 < 4; ++sub2)
          #pragma unroll
          for (int r = 0; r < 4; ++r)
            p[sub2][r] = EXP2F(s[sub2][r]);
        f32x4 t4 = p[0] + p[1] + p[2] + p[3];
        lS += (t4[0] + t4[1]) + (t4[2] + t4[3]);

        #pragma unroll
        for (int sub2 = 0; sub2 < 4; ++sub2) {
          bf16x4 pk;
          pk[0] = (bf16)p[sub2][0]; pk[1] = (bf16)p[sub2][1];
          pk[2] = (bf16)p[sub2][2]; pk[3] = (bf16)p[sub2][3];
          *(bf16x4*)(pw + (((sub2 << 5) + (lg << 3)) ^ psw)) = pk;
        }

        __builtin_amdgcn_s_setprio(1);
        #pragma unroll
        for (int kc = 0; kc < 2; ++kc) {
          bf16x8 pa = *(const bf16x8*)(pw + (((kc << 6) + (lg << 4)) ^ psw));
          #pragma unroll
          for (int d = 0; d < 4; ++d) {
            const char* vr = vbase + ((d << 4) + li) * 128;
            bf16x8 vb = *(const bf16x8*)(vr + ((((kc << 2) + lg) ^ (li & 7)) << 4));
            zacc[d] = MFMA(pa, vb, zacc[d]);
          }
        }
        __builtin_amdgcn_s_setprio(0);
      }

      __syncthreads();
    }

    lS += __shfl_xor(lS, 16);
    lS += __shfl_xor(lS, 32);

    float rls[4];
    #pragma unroll
    for (int r = 0; r < 4; ++r) rls[r] = 1.0f / __shfl(lS, (lg << 2) + r);
    bf16* zp = z + (tb + qw) * 1024 + (h << 6);
    #pragma unroll
    for (int d = 0; d < 4; ++d)
      #pragma unroll
      for (int r = 0; r < 4; ++r)
        zp[(size_t)((lg << 2) + r) * 1024 + (d << 4) + li] = (bf16)(zacc[d][r] * rls[r]);
  }
}

// ---------------- launch ----------------------------------------------------
extern "C" void kernel_launch(void* const* d_in, const int* in_sizes, int n_in,
                              void* d_out, int out_size, void* d_ws, size_t ws_size,
                              hipStream_t stream)
{
  const float* x     = (const float*)d_in[0];
  const float* W_K   = (const float*)d_in[1];
  const float* W_Q   = (const float*)d_in[2];
  const float* W_V   = (const float*)d_in[3];
  const float* W_O   = (const float*)d_in[4];
  const float* W_in  = (const float*)d_in[5];
  const float* b_in  = (const float*)d_in[6];
  const float* W_out = (const float*)d_in[7];
  const float* b_out = (const float*)d_in[8];
  float* out = (float*)d_out;

  char* ws = (char*)d_ws;
  bf16*  xb   = (bf16*)ws;  ws += (size_t)8192*1024*2;
  bf16*  wqkv = (bf16*)ws;  ws += (size_t)3072*1024*2;
  bf16*  wo   = (bf16*)ws;  ws += (size_t)1024*1024*2;
  bf16*  win  = (bf16*)ws;  ws += (size_t)4096*1024*2;
  bf16*  wout = (bf16*)ws;  ws += (size_t)1024*4096*2;
  bf16*  qkv  = (bf16*)ws;  ws += (size_t)8192*3072*2;
  bf16*  zb   = (bf16*)ws;  ws += (size_t)8192*1024*2;
  bf16*  x1b  = (bf16*)ws;  ws += (size_t)8192*1024*2;
  bf16*  hb   = (bf16*)ws;  // 8192*4096*2
  bf16*  vtb  = hb;         // alias: vt[64][64][2048] used before MLP1 writes hb

  CastSegs cs;
  const float* srcs[7] = { x, W_Q, W_K, W_V, W_O, W_in, W_out };
  bf16* dsts[7] = { xb, wqkv, wqkv + 1024*1024, wqkv + 2048*1024, wo, win, wout };
  int n8s[7] = { 1048576, 131072, 131072, 131072, 131072, 524288, 524288 };
  int cum = 0;
  for (int i = 0; i < 7; ++i) { cs.src[i] = srcs[i]; cs.dst[i] = dsts[i]; cs.cum[i] = cum; cum += n8s[i]; }
  cs.cum[7] = cum;
  cast_multi<<<dim3((cum + 255) / 256), dim3(256), 0, stream>>>(cs);

  // QKV = x @ Wqkv^T  [8192 x 3072]  (256x128, 768 blocks = 3 exact rounds)
  gemm128n<0><<<dim3(768), 512, 0, stream>>>(xb, wqkv, nullptr, qkv, nullptr, nullptr, vtb, 8192, 3072, 1024, 24);
  // causal attention -> z [8192 x 1024]  (512 blocks x 8 waves, v8)
  attn_kernel<<<dim3(512), 512, 0, stream>>>(qkv, vtb, zb);
  // x1 = z @ W_O^T + x  -> bf16  (256x128, 256 blocks = 1 round)
  gemm128n<1><<<dim3(256), 512, 0, stream>>>(zb, wo, nullptr, x1b, xb, nullptr, nullptr, 8192, 1024, 1024, 8);
  // h = gelu(x1 @ W_in^T + b_in)  (256^2, 512 blocks = 2 exact rounds)
  gemm256<2><<<dim3(512), 512, 0, stream>>>(x1b, win, nullptr, hb, nullptr, b_in, nullptr, 8192, 4096, 1024, 16);
  // out = x1 + h @ W_out^T + b_out  (256x128, K=4096, 256 blocks = 1 round)
  gemm128n<3><<<dim3(256), 512, 0, stream>>>(hb, wout, out, nullptr, x1b, b_out, nullptr, 8192, 1024, 4096, 8);
}

// Round 21
// 282.995 us; speedup vs baseline: 1.0128x; 1.0128x over previous
//
#include <hip/hip_runtime.h>
#include <hip/hip_bf16.h>

typedef __bf16 bf16;
typedef __bf16 bf16x8 __attribute__((ext_vector_type(8)));
typedef __bf16 bf16x4 __attribute__((ext_vector_type(4)));
typedef float  f32x4  __attribute__((ext_vector_type(4)));

#define MFMA(a,b,c) __builtin_amdgcn_mfma_f32_16x16x32_bf16(a,b,c,0,0,0)
#define EXP2F(x) __builtin_amdgcn_exp2f(x)

__device__ __forceinline__ void gload16(const void* g, void* l) {
  __builtin_amdgcn_global_load_lds((__attribute__((address_space(1))) void*)(g),
                                   (__attribute__((address_space(3))) void*)(l), 16, 0, 0);
}

// ---------------- fused fp32 -> bf16 cast (7 segments, one launch) ----------
struct CastSegs {
  const float* src[7];
  bf16* dst[7];
  int cum[8];
};

__global__ void cast_multi(CastSegs s) {
  int i = blockIdx.x * 256 + threadIdx.x;
  if (i >= s.cum[7]) return;
  int k = 0;
  #pragma unroll
  for (int j = 1; j < 7; ++j) if (i >= s.cum[j]) k = j;
  int off = i - s.cum[k];
  const float4* p = (const float4*)s.src[k];
  float4 a = p[2*off], b = p[2*off+1];
  bf16x8 v;
  v[0]=(bf16)a.x; v[1]=(bf16)a.y; v[2]=(bf16)a.z; v[3]=(bf16)a.w;
  v[4]=(bf16)b.x; v[5]=(bf16)b.y; v[6]=(bf16)b.z; v[7]=(bf16)b.w;
  *(bf16x8*)(s.dst[k] + (size_t)8*off) = v;
}

__device__ __forceinline__ float gelu_t(float s) {
  float u = s * (0.7978845608f + 0.0356774081f * s * s);
  return s / (1.0f + EXP2F(-2.885390082f * u));
}

#define LGKM0_FENCE() { asm volatile("s_waitcnt lgkmcnt(0)" ::: "memory"); \
                        __builtin_amdgcn_sched_barrier(0); }

// Shared epilogue semantics (both GEMM kernels):
// EPI 0: QKV — K/Q blocks -> outb bf16; V blocks (n0>=2048) -> vt[bh][dd][p]
// EPI 1: + addb (bf16) -> outb bf16           [W_O: x1 = z@Wo + x]
// EPI 2: + bias, GELU -> outb bf16            [MLP1]
// EPI 3: + bias + addb (bf16) -> outf f32     [MLP2 final]

// ============ 256x256 8-phase GEMM (merged barriers), C = A @ B^T ===========
#define LDA_PH(MI2) { _Pragma("unroll") for (int i = 0; i < 4; i++) { \
    af[i][0] = *(const bf16x8*)(lds + ab + ((((MI2)<<2)+i) << 11) + rdswz); \
    af[i][1] = *(const bf16x8*)(lds + ab + ((((MI2)<<2)+i) << 11) + 1024 + rdswz); } }

#define LDB_PH(NI2) { _Pragma("unroll") for (int n = 0; n < 2; n++) { \
    bfr[((NI2)<<1)+n][0] = *(const bf16x8*)(lds + bb + (((((NI2)<<1)+n)) << 11) + rdswz); \
    bfr[((NI2)<<1)+n][1] = *(const bf16x8*)(lds + bb + (((((NI2)<<1)+n)) << 11) + 1024 + rdswz); } }

#define MM_PH(MI2, NI2) { __builtin_amdgcn_s_setprio(1); \
    _Pragma("unroll") for (int i = 0; i < 4; i++) \
      _Pragma("unroll") for (int n = 0; n < 2; n++) { \
        acc[((MI2)<<2)+i][((NI2)<<1)+n] = MFMA(af[i][0], bfr[((NI2)<<1)+n][0], acc[((MI2)<<2)+i][((NI2)<<1)+n]); \
        acc[((MI2)<<2)+i][((NI2)<<1)+n] = MFMA(af[i][1], bfr[((NI2)<<1)+n][1], acc[((MI2)<<2)+i][((NI2)<<1)+n]); } \
    __builtin_amdgcn_s_setprio(0); }

#define GTILE(CUR, S1, S2, VM) { \
    const int ab = ((CUR) << 16) + (wm << 14); \
    const int bb = ((CUR) << 16) + 32768 + (wn << 13); \
    LDA_PH(0); LDB_PH(0); \
    if (S1) STG(sA, (CUR)^1, 0, 1, t + 1); \
    asm volatile("s_waitcnt lgkmcnt(8)" ::: "memory"); \
    __builtin_amdgcn_s_barrier(); LGKM0_FENCE(); \
    MM_PH(0, 0); \
    LDB_PH(1); \
    if (S2) STG(sB, (CUR), 1, 0, t + 2); \
    __builtin_amdgcn_s_barrier(); LGKM0_FENCE(); \
    MM_PH(0, 1); \
    LDA_PH(1); \
    if (S2) STG(sB, (CUR), 1, 1, t + 2); \
    __builtin_amdgcn_s_barrier(); LGKM0_FENCE(); \
    MM_PH(1, 0); \
    if (S2) STG(sA, (CUR), 0, 0, t + 2); \
    MM_PH(1, 1); \
    asm volatile("s_waitcnt vmcnt(" #VM ")" ::: "memory"); \
    __builtin_amdgcn_s_barrier(); \
    __builtin_amdgcn_sched_barrier(0); }

template<int EPI>
__global__ __launch_bounds__(512, 2) void gemm256(
    const bf16* __restrict__ A, const bf16* __restrict__ B,
    float* __restrict__ outf, bf16* __restrict__ outb,
    const bf16* __restrict__ addb, const float* __restrict__ bias,
    bf16* __restrict__ vtb,
    int M, int N, int K, int gx)
{
  __shared__ __attribute__((aligned(128))) char lds[131072];
  const int tid = threadIdx.x;
  const int w = tid >> 6, l = tid & 63, lg = l >> 4, li = l & 15;
  const int wm = w >> 2, wn = w & 3;

  const int nwg = gridDim.x, orig = blockIdx.x;
  const int q = nwg >> 3, r = nwg & 7;
  const int xcd = orig & 7, pos = orig >> 3;
  const int wg = (xcd < r ? xcd*(q+1) : r*(q+1) + (xcd-r)*q) + pos;
  const int m0 = (wg / gx) << 8, n0 = (wg % gx) << 8;

  const int NT = K >> 6;

  const int srow = ((tid >> 7) << 4) + ((tid >> 2) & 15);
  const int scol = (((tid >> 6) & 1) << 5) + (((tid & 3) << 3) ^ (((tid >> 5) & 1) << 4));
  const bf16* sA = A + (size_t)(m0 + srow) * K + scol;
  const bf16* sB = B + (size_t)(n0 + srow) * K + scol;
  char* const myl = lds + (w << 10);

  auto STG = [&](const bf16* s0, int buf, int isB, int h, int tt) {
    const bf16* g = s0 + ((size_t)(h << 7)) * K + ((size_t)tt << 6);
    char* lb = myl + (buf << 16) + (isB << 15) + (h << 14);
    gload16(g, lb);
    gload16(g + ((size_t)K << 6), lb + 8192);
  };

  const int rdswz = (li << 6) + ((lg << 4) ^ ((li & 8) << 2));

  f32x4 acc[8][4] = {};
  bf16x8 af[4][2], bfr[4][2];

  STG(sB, 0, 1, 0, 0); STG(sB, 0, 1, 1, 0); STG(sA, 0, 0, 0, 0); STG(sA, 0, 0, 1, 0);
  asm volatile("s_waitcnt vmcnt(4)" ::: "memory");
  STG(sB, 1, 1, 0, 1); STG(sB, 1, 1, 1, 1); STG(sA, 1, 0, 0, 1);
  asm volatile("s_waitcnt vmcnt(6)" ::: "memory");
  __builtin_amdgcn_s_barrier();
  __builtin_amdgcn_sched_barrier(0);

  int t = 0;
  for (int tt = 0; tt + 3 < NT; tt += 2) {
    t = tt;     GTILE(0, 1, 1, 6);
    t = tt + 1; GTILE(1, 1, 1, 6);
  }
  t = NT - 2; GTILE(0, 1, 0, 0);
  t = NT - 1; GTILE(1, 0, 0, 0);

  if (EPI == 0 && n0 >= 2048) {
    #pragma unroll
    for (int mi = 0; mi < 8; mi++) {
      const int row = m0 + (wm << 7) + (mi << 4) + (lg << 2);
      const int p = row & 2047;
      const size_t bhb = (size_t)((row >> 11) << 4);
      #pragma unroll
      for (int ni = 0; ni < 4; ni++) {
        const int col = n0 + (wn << 6) + (ni << 4) + li;
        const int hh = (col >> 6) & 15, dd = col & 63;
        bf16x4 pk;
        pk[0] = (bf16)acc[mi][ni][0]; pk[1] = (bf16)acc[mi][ni][1];
        pk[2] = (bf16)acc[mi][ni][2]; pk[3] = (bf16)acc[mi][ni][3];
        *(bf16x4*)(vtb + ((bhb + hh) * 64 + dd) * 2048 + p) = pk;
      }
    }
    return;
  }

  #pragma unroll
  for (int mi = 0; mi < 8; mi++) {
    const int row = m0 + (wm << 7) + (mi << 4) + (lg << 2);
    #pragma unroll
    for (int ni = 0; ni < 4; ni++) {
      const int col = n0 + (wn << 6) + (ni << 4) + li;
      #pragma unroll
      for (int r2 = 0; r2 < 4; r2++) {
        const size_t idx = (size_t)(row + r2) * N + col;
        float v = acc[mi][ni][r2];
        if (EPI == 0) {
          outb[idx] = (bf16)v;
        } else if (EPI == 1) {
          outb[idx] = (bf16)(v + (float)addb[idx]);
        } else if (EPI == 2) {
          outb[idx] = (bf16)gelu_t(v + bias[col]);
        } else {
          outf[idx] = v + bias[col] + (float)addb[idx];
        }
      }
    }
  }
}

// ============ 256x128 8-phase GEMM (merged barriers), C = A @ B^T ===========
#define N_LDA2(BMI) { _Pragma("unroll") for (int i = 0; i < 2; i++) { \
    af[i][0] = *(const bf16x8*)(lds + abase + (((BMI)+i) << 11) + rdswz); \
    af[i][1] = *(const bf16x8*)(lds + abase + (((BMI)+i) << 11) + 1024 + rdswz); } }

#define N_LDB2(BNI) { _Pragma("unroll") for (int n = 0; n < 2; n++) { \
    bfr[(BNI)+n][0] = *(const bf16x8*)(lds + bbase + (((BNI)+n) << 11) + rdswz); \
    bfr[(BNI)+n][1] = *(const bf16x8*)(lds + bbase + (((BNI)+n) << 11) + 1024 + rdswz); } }

#define N_MMQ(MB, NB) { __builtin_amdgcn_s_setprio(1); \
    _Pragma("unroll") for (int i = 0; i < 2; i++) \
      _Pragma("unroll") for (int n = 0; n < 2; n++) { \
        acc[((MB)<<1)+i][((NB)<<1)+n] = MFMA(af[i][0], bfr[((NB)<<1)+n][0], acc[((MB)<<1)+i][((NB)<<1)+n]); \
        acc[((MB)<<1)+i][((NB)<<1)+n] = MFMA(af[i][1], bfr[((NB)<<1)+n][1], acc[((MB)<<1)+i][((NB)<<1)+n]); } \
    __builtin_amdgcn_s_setprio(0); }

#define NTILE(CUR, S1, S2, VM) { \
    const int abase = (CUR) * 49152 + ((wm >> 1) << 14) + ((wm & 1) << 13); \
    const int bbase = (CUR) * 49152 + 32768 + (wn << 13); \
    N_LDA2(0); N_LDB2(0); \
    if (S1) STA((CUR)^1, 1, t + 1); \
    __builtin_amdgcn_s_barrier(); LGKM0_FENCE(); \
    N_MMQ(0, 0); \
    N_LDB2(2); \
    if (S2) STB((CUR), 0, t + 2); \
    __builtin_amdgcn_s_barrier(); LGKM0_FENCE(); \
    N_MMQ(0, 1); \
    N_LDA2(2); \
    if (S2) STB((CUR), 1, t + 2); \
    __builtin_amdgcn_s_barrier(); LGKM0_FENCE(); \
    N_MMQ(1, 0); \
    if (S2) STA((CUR), 0, t + 2); \
    N_MMQ(1, 1); \
    asm volatile("s_waitcnt vmcnt(" #VM ")" ::: "memory"); \
    __builtin_amdgcn_s_barrier(); \
    __builtin_amdgcn_sched_barrier(0); }

template<int EPI>
__global__ __launch_bounds__(512, 2) void gemm128n(
    const bf16* __restrict__ A, const bf16* __restrict__ B,
    float* __restrict__ outf, bf16* __restrict__ outb,
    const bf16* __restrict__ addb, const float* __restrict__ bias,
    bf16* __restrict__ vtb,
    int M, int N, int K, int gx)
{
  __shared__ __attribute__((aligned(128))) char lds[98304];
  const int tid = threadIdx.x;
  const int w = tid >> 6, l = tid & 63, lg = l >> 4, li = l & 15;
  const int wm = w >> 1, wn = w & 1;

  const int nwg = gridDim.x, orig = blockIdx.x;
  const int q = nwg >> 3, r = nwg & 7;
  const int xcd = orig & 7, pos = orig >> 3;
  const int wg = (xcd < r ? xcd*(q+1) : r*(q+1) + (xcd-r)*q) + pos;
  const int m0 = (wg / gx) << 8, n0 = (wg % gx) << 7;

  const int NT = K >> 6;

  const int srow = ((tid >> 7) << 4) + ((tid >> 2) & 15);
  const int scol = (((tid >> 6) & 1) << 5) + (((tid & 3) << 3) ^ (((tid >> 5) & 1) << 4));
  const bf16* sA = A + (size_t)(m0 + srow) * K + scol;
  const bf16* sB = B + (size_t)(n0 + srow) * K + scol;
  char* const myl = lds + (w << 10);

  auto STA = [&](int buf, int h, int tt) {
    const bf16* g = sA + ((size_t)(h << 7)) * K + ((size_t)tt << 6);
    char* lb = myl + buf * 49152 + (h << 14);
    gload16(g, lb);
    gload16(g + ((size_t)K << 6), lb + 8192);
  };
  auto STB = [&](int buf, int h, int tt) {
    const bf16* g = sB + ((size_t)(h << 6)) * K + ((size_t)tt << 6);
    gload16(g, myl + buf * 49152 + 32768 + (h << 13));
  };

  const int rdswz = (li << 6) + ((lg << 4) ^ ((li & 8) << 2));

  f32x4 acc[4][4] = {};
  bf16x8 af[2][2], bfr[4][2];

  STB(0, 0, 0); STB(0, 1, 0); STA(0, 0, 0); STA(0, 1, 0);
  STB(1, 0, 1); STB(1, 1, 1); STA(1, 0, 1);
  asm volatile("s_waitcnt vmcnt(4)" ::: "memory");
  __builtin_amdgcn_s_barrier();
  __builtin_amdgcn_sched_barrier(0);

  int t = 0;
  for (int tt = 0; tt + 3 < NT; tt += 2) {
    t = tt;     NTILE(0, 1, 1, 4);
    t = tt + 1; NTILE(1, 1, 1, 4);
  }
  t = NT - 2; NTILE(0, 1, 0, 0);
  t = NT - 1; NTILE(1, 0, 0, 0);

  if (EPI == 0 && n0 >= 2048) {
    #pragma unroll
    for (int mi = 0; mi < 4; mi++) {
      const int row = m0 + (wm << 6) + (mi << 4) + (lg << 2);
      const int p = row & 2047;
      const size_t bhb = (size_t)((row >> 11) << 4);
      #pragma unroll
      for (int ni = 0; ni < 4; ni++) {
        const int col = n0 + (wn << 6) + (ni << 4) + li;
        const int hh = (col >> 6) & 15, dd = col & 63;
        bf16x4 pk;
        pk[0] = (bf16)acc[mi][ni][0]; pk[1] = (bf16)acc[mi][ni][1];
        pk[2] = (bf16)acc[mi][ni][2]; pk[3] = (bf16)acc[mi][ni][3];
        *(bf16x4*)(vtb + ((bhb + hh) * 64 + dd) * 2048 + p) = pk;
      }
    }
    return;
  }

  #pragma unroll
  for (int mi = 0; mi < 4; mi++) {
    const int row = m0 + (wm << 6) + (mi << 4) + (lg << 2);
    #pragma unroll
    for (int ni = 0; ni < 4; ni++) {
      const int col = n0 + (wn << 6) + (ni << 4) + li;
      #pragma unroll
      for (int r2 = 0; r2 < 4; r2++) {
        const size_t idx = (size_t)(row + r2) * N + col;
        float v = acc[mi][ni][r2];
        if (EPI == 0) {
          outb[idx] = (bf16)v;
        } else if (EPI == 1) {
          outb[idx] = (bf16)(v + (float)addb[idx]);
        } else if (EPI == 2) {
          outb[idx] = (bf16)gelu_t(v + bias[col]);
        } else {
          outf[idx] = v + bias[col] + (float)addb[idx];
        }
      }
    }
  }
}

// ---------------- causal flash attention (v8: KVBLK=128, 8-wave blocks) ------
__global__ __launch_bounds__(512, 2) void attn_kernel(const bf16* __restrict__ qkv,
                                                      const bf16* __restrict__ vt,
                                                      bf16* __restrict__ z)
{
  __shared__ bf16 Ksh[2][2*64*64];
  __shared__ bf16 Vsh[2][2*64*64];
  __shared__ bf16 Pl[8*16*64];

  const int tid = threadIdx.x;
  const int w = tid >> 6, l = tid & 63, lg = l >> 4, li = l & 15;
  const int orig = blockIdx.x;
  const int xcd = orig & 7, sub = orig >> 3;
  const int bh = (xcd << 3) + (sub >> 3);
  const int pr = sub & 7;
  const int h = bh & 15, b = bh >> 4;
  const size_t tb = (size_t)b * 2048;

  const int srow = tid >> 3, sc = tid & 7;
  const bf16* Kg = qkv + (tb + srow) * 3072 + 1024 + (h << 6) + ((sc ^ (srow & 7)) << 3);
  const bf16* Vg = vt + ((size_t)bh * 64 + srow) * 2048 + ((sc ^ (srow & 7)) << 3);

  char* pw = (char*)Pl + (w << 11) + li * 128;
  const int psw = (li & 3) << 5;

  for (int hf = 0; hf < 2; ++hf) {
    const int qt = hf ? pr : (15 - pr);
    const int qw = (qt << 7) + (w << 4);

    const bf16* Qp = qkv + (tb + qw + li) * 3072 + (h << 6);
    bf16x8 qa0 = *(const bf16x8*)(Qp + (lg << 3));
    bf16x8 qa1 = *(const bf16x8*)(Qp + 32 + (lg << 3));
    #pragma unroll
    for (int e = 0; e < 8; e++) {
      qa0[e] = (bf16)((float)qa0[e] * 0.1803368801f);
      qa1[e] = (bf16)((float)qa1[e] * 0.1803368801f);
    }

    f32x4 zacc[4] = {};
    float lS = 0.f;
    const int nkt = qt + 1;

    gload16(Kg,                    (bf16*)Ksh[0] + (w << 9));
    gload16(Kg + (size_t)64*3072,  (bf16*)Ksh[0] + 4096 + (w << 9));
    gload16(Vg,                    (bf16*)Vsh[0] + (w << 9));
    gload16(Vg + 64,               (bf16*)Vsh[0] + 4096 + (w << 9));
    __syncthreads();

    for (int kt = 0; kt < nkt; ++kt) {
      const int cur = kt & 1;
      const int kb = kt << 7;

      if (kt + 1 < nkt) {
        const int nb = cur ^ 1;
        gload16(Kg + (size_t)(kb + 128) * 3072, (bf16*)Ksh[nb] + (w << 9));
        gload16(Kg + (size_t)(kb + 192) * 3072, (bf16*)Ksh[nb] + 4096 + (w << 9));
        gload16(Vg + kb + 128,                  (bf16*)Vsh[nb] + (w << 9));
        gload16(Vg + kb + 192,                  (bf16*)Vsh[nb] + 4096 + (w << 9));
      }

      #pragma unroll
      for (int half = 0; half < 2; ++half) {
        const int pb = kb + (half << 6);
        const char* kbase = (const char*)Ksh[cur] + (half << 13);
        const char* vbase = (const char*)Vsh[cur] + (half << 13);

        f32x4 s[4];
        __builtin_amdgcn_s_setprio(1);
        #pragma unroll
        for (int sub2 = 0; sub2 < 4; ++sub2) {
          const char* kr = kbase + ((sub2 << 4) + li) * 128;
          const int c0 = (lg ^ (li & 7)) << 4;
          bf16x8 kb0 = *(const bf16x8*)(kr + c0);
          bf16x8 kb1 = *(const bf16x8*)(kr + (c0 ^ 64));
          f32x4 a2 = {};
          a2 = MFMA(kb0, qa0, a2);
          a2 = MFMA(kb1, qa1, a2);
          s[sub2] = a2;
        }
        __builtin_amdgcn_s_setprio(0);

        if (pb + 63 > qw) {
          #pragma unroll
          for (int sub2 = 0; sub2 < 4; ++sub2)
            #pragma unroll
            for (int r = 0; r < 4; ++r)
              if (pb + (sub2 << 4) + (lg << 2) + r > qw + li) s[sub2][r] = -1e30f;
        }

        f32x4 p[4];
        #pragma unroll
        for (int sub2 = 0; sub2 < 4; ++sub2)
          #pragma unroll
          for (int r = 0; r < 4; ++r)
            p[sub2][r] = EXP2F(s[sub2][r]);
        f32x4 t4 = p[0] + p[1] + p[2] + p[3];
        lS += (t4[0] + t4[1]) + (t4[2] + t4[3]);

        #pragma unroll
        for (int sub2 = 0; sub2 < 4; ++sub2) {
          bf16x4 pk;
          pk[0] = (bf16)p[sub2][0]; pk[1] = (bf16)p[sub2][1];
          pk[2] = (bf16)p[sub2][2]; pk[3] = (bf16)p[sub2][3];
          *(bf16x4*)(pw + (((sub2 << 5) + (lg << 3)) ^ psw)) = pk;
        }

        __builtin_amdgcn_s_setprio(1);
        #pragma unroll
        for (int kc = 0; kc < 2; ++kc) {
          bf16x8 pa = *(const bf16x8*)(pw + (((kc << 6) + (lg << 4)) ^ psw));
          #pragma unroll
          for (int d = 0; d < 4; ++d) {
            const char* vr = vbase + ((d << 4) + li) * 128;
            bf16x8 vb = *(const bf16x8*)(vr + ((((kc << 2) + lg) ^ (li & 7)) << 4));
            zacc[d] = MFMA(pa, vb, zacc[d]);
          }
        }
        __builtin_amdgcn_s_setprio(0);
      }

      __syncthreads();
    }

    lS += __shfl_xor(lS, 16);
    lS += __shfl_xor(lS, 32);

    float rls[4];
    #pragma unroll
    for (int r = 0; r < 4; ++r) rls[r] = 1.0f / __shfl(lS, (lg << 2) + r);
    bf16* zp = z + (tb + qw) * 1024 + (h << 6);
    #pragma unroll
    for (int d = 0; d < 4; ++d)
      #pragma unroll
      for (int r = 0; r < 4; ++r)
        zp[(size_t)((lg << 2) + r) * 1024 + (d << 4) + li] = (bf16)(zacc[d][r] * rls[r]);
  }
}

// ---------------- launch ----------------------------------------------------
extern "C" void kernel_launch(void* const* d_in, const int* in_sizes, int n_in,
                              void* d_out, int out_size, void* d_ws, size_t ws_size,
                              hipStream_t stream)
{
  const float* x     = (const float*)d_in[0];
  const float* W_K   = (const float*)d_in[1];
  const float* W_Q   = (const float*)d_in[2];
  const float* W_V   = (const float*)d_in[3];
  const float* W_O   = (const float*)d_in[4];
  const float* W_in  = (const float*)d_in[5];
  const float* b_in  = (const float*)d_in[6];
  const float* W_out = (const float*)d_in[7];
  const float* b_out = (const float*)d_in[8];
  float* out = (float*)d_out;

  char* ws = (char*)d_ws;
  bf16*  xb   = (bf16*)ws;  ws += (size_t)8192*1024*2;
  bf16*  wqkv = (bf16*)ws;  ws += (size_t)3072*1024*2;
  bf16*  wo   = (bf16*)ws;  ws += (size_t)1024*1024*2;
  bf16*  win  = (bf16*)ws;  ws += (size_t)4096*1024*2;
  bf16*  wout = (bf16*)ws;  ws += (size_t)1024*4096*2;
  bf16*  qkv  = (bf16*)ws;  ws += (size_t)8192*3072*2;
  bf16*  zb   = (bf16*)ws;  ws += (size_t)8192*1024*2;
  bf16*  x1b  = (bf16*)ws;  ws += (size_t)8192*1024*2;
  bf16*  hb   = (bf16*)ws;  // 8192*4096*2
  bf16*  vtb  = hb;         // alias: vt[64][64][2048] used before MLP1 writes hb

  CastSegs cs;
  const float* srcs[7] = { x, W_Q, W_K, W_V, W_O, W_in, W_out };
  bf16* dsts[7] = { xb, wqkv, wqkv + 1024*1024, wqkv + 2048*1024, wo, win, wout };
  int n8s[7] = { 1048576, 131072, 131072, 131072, 131072, 524288, 524288 };
  int cum = 0;
  for (int i = 0; i < 7; ++i) { cs.src[i] = srcs[i]; cs.dst[i] = dsts[i]; cs.cum[i] = cum; cum += n8s[i]; }
  cs.cum[7] = cum;
  cast_multi<<<dim3((cum + 255) / 256), dim3(256), 0, stream>>>(cs);

  // QKV = x @ Wqkv^T  [8192 x 3072]  (256x128, 768 blocks = 3 exact rounds)
  gemm128n<0><<<dim3(768), 512, 0, stream>>>(xb, wqkv, nullptr, qkv, nullptr, nullptr, vtb, 8192, 3072, 1024, 24);
  // causal attention -> z [8192 x 1024]  (512 blocks x 8 waves, v8)
  attn_kernel<<<dim3(512), 512, 0, stream>>>(qkv, vtb, zb);
  // x1 = z @ W_O^T + x  -> bf16  (256x128, 256 blocks = 1 round)
  gemm128n<1><<<dim3(256), 512, 0, stream>>>(zb, wo, nullptr, x1b, xb, nullptr, nullptr, 8192, 1024, 1024, 8);
  // h = gelu(x1 @ W_in^T + b_in)  (256^2, 512 blocks = 2 exact rounds)
  gemm256<2><<<dim3(512), 512, 0, stream>>>(x1b, win, nullptr, hb, nullptr, b_in, nullptr, 8192, 4096, 1024, 16);
  // out = x1 + h @ W_out^T + b_out  (256x128, K=4096, 256 blocks = 1 round)
  gemm128n<3><<<dim3(256), 512, 0, stream>>>(hb, wout, out, nullptr, x1b, b_out, nullptr, 8192, 1024, 4096, 8);
}